// Round 11
// baseline (318.001 us; speedup 1.0000x reference)
//
#include <hip/hip_runtime.h>
#include <hip/hip_bf16.h>

#define N_NODES 100000
#define N_EDGES 1600000
#define IN_C 128
#define C 64            // hid_c == out_c
#define NBKT 196        // coarse buckets: dst>>9 (512 dsts each)
#define CAP 9216        // bucket capacity: mean 8192, +11 sigma slack
#define BCHK 4000       // edges per bucket block (32 KB stage)
#define NBB (N_EDGES / BCHK)   // 400 bucket blocks
#define GB1 (N_NODES / 32)     // 3125 gemm1 blocks

typedef float vfloat2 __attribute__((ext_vector_type(2)));

__device__ __forceinline__ float bfu2f(unsigned short u) {
    return __uint_as_float(((unsigned int)u) << 16);
}
__device__ __forceinline__ unsigned short f2bfu(float f) {
    __hip_bfloat16 h = __float2bfloat16(f);
    unsigned short u; __builtin_memcpy(&u, &h, 2); return u;
}
// bf16x2 unpack, 1 VALU op each
__device__ __forceinline__ float blo(unsigned int v) { return __uint_as_float(v << 16); }
__device__ __forceinline__ float bhi(unsigned int v) { return __uint_as_float(v & 0xFFFF0000u); }
// 15-bit weight decode: w in [1, ~3.42), rel err ~3e-5
__device__ __forceinline__ float dec_w(unsigned int p) {
    return __uint_as_float(((p & 0x7FFFu) + 0x1FC000u) << 9);
}
__device__ __forceinline__ float load_f(const void* p, int i, int f32) {
    return f32 ? ((const float*)p)[i] : bfu2f(((const unsigned short*)p)[i]);
}
__device__ __forceinline__ int load_idx(const void* ei, size_t i, int i64) {
    return i64 ? (int)((const long long*)ei)[i] : ((const int*)ei)[i];
}

// ---- runtime dtype detection + gcnt zeroing (saves a memset launch) -------
__global__ __launch_bounds__(256) void k_detect(
    const uint4* __restrict__ x4, const int* __restrict__ ei32,
    int* __restrict__ flags, int* __restrict__ gcnt)
{
    __shared__ int cff, cnz;
    int t = threadIdx.x;
    gcnt[t] = 0;                                 // 256 ints >= NBKT
    if (t == 0) { cff = 0; cnz = 0; }
    __syncthreads();
    int lff = 0;
    #pragma unroll
    for (int j = 0; j < 16; ++j) {               // 16384 dwords of x
        uint4 w = x4[t + j * 256];
        unsigned int a[4] = {w.x, w.y, w.z, w.w};
        #pragma unroll
        for (int q = 0; q < 4; ++q) {
            // fp32 data: low mantissa half as pseudo-bf16 exponent hits 0xFF
            // w.p. 1/256 per dword; bf16 pairs never have exp==0xFF (no inf/NaN)
            if ((a[q] & 0x00007F80u) == 0x00007F80u) lff++;
            if ((a[q] & 0x7F800000u) == 0x7F800000u) lff++;
        }
    }
    int lnz = 0;
    for (int i = t; i < 2048; i += 256)
        if (ei32[2 * i + 1] != 0) lnz++;
    if (lff) atomicAdd(&cff, lff);
    if (lnz) atomicAdd(&cnz, lnz);
    __syncthreads();
    if (t == 0) {
        flags[0] = (cff > 0) ? 1 : 0;   // 1 = fp32 floats (confirmed on HW)
        flags[1] = (cnz == 0) ? 1 : 0;  // 1 = int64 indices (HW: int32)
    }
}

// ---- FAT kernel: blocks [0,NBB) = bucket sort; [NBB, NBB+GB1) = GEMM1 -----
// R10 post-mortem: occupancy fix (19->38%) gave only -5 us => the binder is
// gemm1's LDS instruction issue (FMA:b128 ratio 3.2). This version: 2x4
// register tile -> 6 b128 per 32 FMA (ratio 5.3, 1.67x fewer LDS instrs).
// LDS = 16.4 (xs) + 33.8 (full Wls) = 50.2 KB -> 3 blocks/CU.
#define W1_STRIDE (IN_C + 4)   // 132
__global__ __launch_bounds__(256) void k_build_gemm1(
    const void* __restrict__ ea, const void* __restrict__ ei,
    const int* __restrict__ flags, int* __restrict__ gcnt,
    int2* __restrict__ bkt,
    const void* __restrict__ x, const void* __restrict__ W,
    unsigned short* __restrict__ xw)
{
    __shared__ __align__(16) char smem[50176];
    int t = threadIdx.x;
    if (blockIdx.x < NBB) {
        // ---------------- bucket portion ----------------
        int2* stage = (int2*)smem;                    // 4000 x 8B = 32000
        int*  h     = (int*)(smem + 32000);           // 256
        int*  ex    = (int*)(smem + 33024);           // 256
        int*  gb    = (int*)(smem + 34048);           // 256
        int*  ps    = (int*)(smem + 35072);           // 256
        int*  rk    = (int*)(smem + 36096);           // 256
        h[t] = 0; rk[t] = 0;
        __syncthreads();
        int i64 = flags[1], f32 = flags[0];
        int base = blockIdx.x * BCHK;
        #pragma unroll
        for (int i = 0; i < 16; ++i) {               // pass A: histogram
            int ii = i * 256 + t;
            if (ii < BCHK) {
                int d = load_idx(ei, (size_t)N_EDGES + base + ii, i64);
                atomicAdd(&h[d >> 9], 1);
            }
        }
        __syncthreads();
        int hv = h[t];
        ps[t] = hv;
        for (int off = 1; off < 256; off <<= 1) {    // block scan of h
            __syncthreads();
            int val = (t >= off) ? ps[t - off] : 0;
            __syncthreads();
            ps[t] += val;
        }
        __syncthreads();
        ex[t] = ps[t] - hv;                          // exclusive prefix
        if (t < NBKT) gb[t] = atomicAdd(&gcnt[t], hv);
        __syncthreads();
        #pragma unroll
        for (int i = 0; i < 16; ++i) {               // pass B: rank + stage
            int ii = i * 256 + t;
            if (ii < BCHK) {
                int e = base + ii;
                int d = load_idx(ei, (size_t)N_EDGES + e, i64);
                int s = load_idx(ei, (size_t)e, i64);
                float w = expf(load_f(ea, e, f32));  // unnormalized, [1, e)
                unsigned int wb = __float_as_uint(w);
                int wq = (int)((wb + 0x100u) >> 9) - 0x1FC000;   // 15-bit rnd
                wq = wq < 0 ? 0 : (wq > 0x7FFF ? 0x7FFF : wq);
                int bk2 = d >> 9;
                int r = atomicAdd(&rk[bk2], 1);
                stage[ex[bk2] + r] =
                    make_int2((int)(((unsigned int)s << 15) | (unsigned int)wq), d);
            }
        }
        __syncthreads();
        #pragma unroll
        for (int i = 0; i < 16; ++i) {               // pass C: coalesced flush
            int idx = i * 256 + t;
            if (idx < BCHK) {
                int2 r = stage[idx];
                int bk2 = ((unsigned int)r.y) >> 9;
                int lr = idx - ex[bk2];
                int gi = gb[bk2] + lr;
                if (gi < CAP)                        // fault insurance (+11 sigma)
                    bkt[(size_t)bk2 * CAP + gi] = r;
            }
        }
    } else {
        // ------- GEMM1 portion: 2 rows x 4 cols register tile -------
        int bx = blockIdx.x - NBB;
        float* xs  = (float*)smem;                   // 32*128*4 = 16384
        float* Wls = (float*)(smem + 16384);         // 64*132*4 = 33792
        int f32 = flags[0];
        size_t xbase = (size_t)bx * 32 * IN_C;
        if (f32) {
            const float* xp = (const float*)x + xbase;
            #pragma unroll
            for (int j = 0; j < 16; ++j) { int i = t + j * 256; xs[i] = xp[i]; }
            const float* wp = (const float*)W;
            #pragma unroll
            for (int j = 0; j < 32; ++j) {
                int i = t + j * 256;
                Wls[(i >> 7) * W1_STRIDE + (i & 127)] = wp[i];
            }
        } else {
            const unsigned int* xp = (const unsigned int*)((const unsigned short*)x + xbase);
            #pragma unroll
            for (int j = 0; j < 8; ++j) {
                int i = t + j * 256;
                unsigned int v = xp[i];
                xs[2 * i]     = blo(v);
                xs[2 * i + 1] = bhi(v);
            }
            const unsigned short* wp = (const unsigned short*)W;
            #pragma unroll
            for (int j = 0; j < 32; ++j) {
                int i = t + j * 256;
                Wls[(i >> 7) * W1_STRIDE + (i & 127)] = bfu2f(wp[i]);
            }
        }
        __syncthreads();
        // cg = lane col-group (cols cg, cg+16, cg+32, cg+48: 132-dword lane
        // stride = 2-way bank aliasing = free); rg = row-group (rows 2rg,2rg+1)
        int cg = t & 15, rg = t >> 4;
        const float* xr0 = xs + (rg * 2) * IN_C;
        const float* xr1 = xr0 + IN_C;
        const float* wr  = Wls + cg * W1_STRIDE;
        float acc0[4], acc1[4];
        #pragma unroll
        for (int n = 0; n < 4; ++n) { acc0[n] = 0.f; acc1[n] = 0.f; }
        #pragma unroll
        for (int kk = 0; kk < IN_C / 4; ++kk) {
            float4 x0 = *(const float4*)(xr0 + kk * 4);
            float4 x1 = *(const float4*)(xr1 + kk * 4);
            #pragma unroll
            for (int n = 0; n < 4; ++n) {
                float4 w4 = *(const float4*)(wr + n * 16 * W1_STRIDE + kk * 4);
                acc0[n] += x0.x * w4.x + x0.y * w4.y + x0.z * w4.z + x0.w * w4.w;
                acc1[n] += x1.x * w4.x + x1.y * w4.y + x1.z * w4.z + x1.w * w4.w;
            }
        }
        size_t ob = (size_t)bx * 32 * C + (size_t)(rg * 2) * C + cg;
        #pragma unroll
        for (int n = 0; n < 4; ++n) {
            xw[ob + n * 16]     = f2bfu(acc0[n]);
            xw[ob + C + n * 16] = f2bfu(acc1[n]);
        }
    }
}

// ---- CSR build pass 2: per-bucket fine sort (gcnt scan inlined) -----------
__global__ __launch_bounds__(256) void k_fine(
    const int2* __restrict__ bkt, const int* __restrict__ gcnt,
    int* __restrict__ row_ptr, unsigned int* __restrict__ srt)
{
    __shared__ int h[512], ex[512], ps[256];
    __shared__ int sh_cb;
    int t = threadIdx.x, b = blockIdx.x;
    // inline scan of gcnt[196] -> this block's colbase (replaces k_bktscan)
    int v = (t < NBKT) ? gcnt[t] : 0;
    ps[t] = v;
    for (int off = 1; off < 256; off <<= 1) {
        __syncthreads();
        int val = (t >= off) ? ps[t - off] : 0;
        __syncthreads();
        ps[t] += val;
    }
    __syncthreads();
    if (t == b) sh_cb = ps[t] - v;                   // b < 196 < 256
    if (b == 0 && t == 0) row_ptr[N_NODES] = N_EDGES;
    h[t] = 0; h[t + 256] = 0;
    __syncthreads();
    int nrec = gcnt[b];
    nrec = nrec < CAP ? nrec : CAP;                  // mirror of write clamp
    int cb = sh_cb;
    const int2* bp = bkt + (size_t)b * CAP;
    for (int i = t; i < nrec; i += 256)
        atomicAdd(&h[bp[i].y & 511], 1);
    __syncthreads();
    int s0 = h[2 * t], s1 = h[2 * t + 1];
    ps[t] = s0 + s1;
    for (int off = 1; off < 256; off <<= 1) {
        __syncthreads();
        int val = (t >= off) ? ps[t - off] : 0;
        __syncthreads();
        ps[t] += val;
    }
    __syncthreads();
    int pe = t ? ps[t - 1] : 0;
    ex[2 * t] = pe; ex[2 * t + 1] = pe + s0;
    __syncthreads();
    int d0 = b * 512 + t;
    if (d0 < N_NODES) row_ptr[d0] = cb + ex[t];
    int d1 = d0 + 256;
    if (d1 < N_NODES) row_ptr[d1] = cb + ex[t + 256];
    h[t] = 0; h[t + 256] = 0;                        // reuse h as rank counters
    __syncthreads();
    for (int i = t; i < nrec; i += 256) {
        int2 r = bp[i];
        int dl = r.y & 511;
        int rk = atomicAdd(&h[dl], 1);
        srt[cb + ex[dl] + rk] = (unsigned int)r.x;
    }
}

// ---- GEMM2: h (bf16 internal) @ W2 -> xw (bf16 internal) ------------------
#define W2_STRIDE (C + 4)      // 68
__global__ __launch_bounds__(256) void k_gemm2(
    const unsigned int* __restrict__ h, const void* __restrict__ W,
    const int* __restrict__ flags, unsigned short* __restrict__ xw)
{
    __shared__ float Wls[C * W2_STRIDE];
    __shared__ float xs[32 * C];
    int t = threadIdx.x;
    size_t dwbase = (size_t)blockIdx.x * 32 * 32;   // 32 rows x 32 dwords
    #pragma unroll
    for (int j = 0; j < 4; ++j) {
        int i = t + j * 256;
        unsigned int v = h[dwbase + i];
        xs[2 * i]     = blo(v);
        xs[2 * i + 1] = bhi(v);
    }
    if (flags[0]) {
        const float* wp = (const float*)W;
        #pragma unroll
        for (int j = 0; j < 16; ++j) {
            int i = t + j * 256;
            Wls[(i >> 6) * W2_STRIDE + (i & 63)] = wp[i];
        }
    } else {
        const unsigned short* wp = (const unsigned short*)W;
        #pragma unroll
        for (int j = 0; j < 16; ++j) {
            int i = t + j * 256;
            Wls[(i >> 6) * W2_STRIDE + (i & 63)] = bfu2f(wp[i]);
        }
    }
    __syncthreads();
    int col = t & 63, wv = t >> 6;
    const float* wr = Wls + col * W2_STRIDE;
    const float* xr = xs + wv * 8 * C;
    float acc[8];
    #pragma unroll
    for (int n = 0; n < 8; ++n) acc[n] = 0.f;
    #pragma unroll
    for (int kk = 0; kk < C / 4; ++kk) {
        float4 w4 = *(const float4*)(wr + kk * 4);
        #pragma unroll
        for (int n = 0; n < 8; ++n) {
            float4 x4 = *(const float4*)(xr + n * C + kk * 4);
            acc[n] += x4.x * w4.x + x4.y * w4.y + x4.z * w4.z + x4.w * w4.w;
        }
    }
    size_t obase = (size_t)blockIdx.x * 32 * C + wv * 8 * C + col;
    #pragma unroll
    for (int n = 0; n < 8; ++n) xw[obase + n * C] = f2bfu(acc[n]);
}

// ---- fused msg+update: wave per dst (best measured shape: ~65 us) ---------
// out = sigmoid( (Σ exp_e·xw[src_e]) / (Σ exp_e) + xw[d] + b )
__global__ __launch_bounds__(256) void k_msg_csr(
    const unsigned int* __restrict__ xw, const unsigned int* __restrict__ srt,
    const int* __restrict__ row_ptr, const void* __restrict__ b,
    const int* __restrict__ flags, void* __restrict__ outp, int out_is_final)
{
    int d = blockIdx.x * 4 + (threadIdx.x >> 6);
    int lane = threadIdx.x & 63;
    int half = lane >> 5, li = lane & 31;
    int beg = row_ptr[d], end = row_ptr[d + 1];
    float accx = 0.f, accy = 0.f, asum = 0.f;
    int j = beg;
    for (; j + 8 <= end; j += 8) {
        int jb = j + 4 * half;
        unsigned int p0 = __builtin_nontemporal_load(srt + jb);
        unsigned int p1 = __builtin_nontemporal_load(srt + jb + 1);
        unsigned int p2 = __builtin_nontemporal_load(srt + jb + 2);
        unsigned int p3 = __builtin_nontemporal_load(srt + jb + 3);
        unsigned int v0 = xw[(size_t)(p0 >> 15) * 32 + li];
        unsigned int v1 = xw[(size_t)(p1 >> 15) * 32 + li];
        unsigned int v2 = xw[(size_t)(p2 >> 15) * 32 + li];
        unsigned int v3 = xw[(size_t)(p3 >> 15) * 32 + li];
        float w0 = dec_w(p0), w1 = dec_w(p1), w2 = dec_w(p2), w3 = dec_w(p3);
        accx += w0 * blo(v0) + w1 * blo(v1) + w2 * blo(v2) + w3 * blo(v3);
        accy += w0 * bhi(v0) + w1 * bhi(v1) + w2 * bhi(v2) + w3 * bhi(v3);
        asum += (w0 + w1) + (w2 + w3);
    }
    if (j + 4 <= end) {                       // straight-line tails: 4, 2, 1
        int jb = j + 2 * half;
        unsigned int p0 = __builtin_nontemporal_load(srt + jb);
        unsigned int p1 = __builtin_nontemporal_load(srt + jb + 1);
        unsigned int v0 = xw[(size_t)(p0 >> 15) * 32 + li];
        unsigned int v1 = xw[(size_t)(p1 >> 15) * 32 + li];
        float w0 = dec_w(p0), w1 = dec_w(p1);
        accx += w0 * blo(v0) + w1 * blo(v1);
        accy += w0 * bhi(v0) + w1 * bhi(v1);
        asum += w0 + w1;
        j += 4;
    }
    if (j + 2 <= end) {
        unsigned int p0 = __builtin_nontemporal_load(srt + j + half);
        unsigned int v0 = xw[(size_t)(p0 >> 15) * 32 + li];
        float w0 = dec_w(p0);
        accx += w0 * blo(v0);
        accy += w0 * bhi(v0);
        asum += w0;
        j += 2;
    }
    if (j < end && half == 0) {
        unsigned int p0 = __builtin_nontemporal_load(srt + j);
        unsigned int v0 = xw[(size_t)(p0 >> 15) * 32 + li];
        float w0 = dec_w(p0);
        accx += w0 * blo(v0);
        accy += w0 * bhi(v0);
        asum += w0;
    }
    accx += __shfl_xor(accx, 32);
    accy += __shfl_xor(accy, 32);
    asum += __shfl_xor(asum, 32);
    float inv = (end > beg) ? 1.f / asum : 0.f;
    unsigned int sv = xw[(size_t)d * 32 + li];
    int f32 = flags[0];
    float b0 = load_f(b, 2 * li, f32), b1 = load_f(b, 2 * li + 1, f32);
    float v0 = accx * inv + blo(sv) + b0;
    float v1 = accy * inv + bhi(sv) + b1;
    float r0 = 1.f / (1.f + expf(-v0));
    float r1 = 1.f / (1.f + expf(-v1));
    if (half == 0) {
        if (out_is_final && f32) {
            vfloat2 rv; rv.x = r0; rv.y = r1;
            __builtin_nontemporal_store(rv, (vfloat2*)outp + (size_t)d * 32 + li);
        } else {
            unsigned int packed = (unsigned int)f2bfu(r0) | ((unsigned int)f2bfu(r1) << 16);
            __builtin_nontemporal_store(packed, (unsigned int*)outp + (size_t)d * 32 + li);
        }
    }
}

extern "C" void kernel_launch(void* const* d_in, const int* in_sizes, int n_in,
                              void* d_out, int out_size, void* d_ws, size_t ws_size,
                              hipStream_t stream) {
    const void* x  = d_in[0];
    const void* ei = d_in[1];
    const void* ea = d_in[2];
    const void* W1 = d_in[3];
    const void* b1 = d_in[4];
    const void* W2 = d_in[5];
    const void* b2 = d_in[6];

    char* base = (char*)d_ws;
    int*            flags   = (int*)base;                   // 256 B
    int*            gcnt    = (int*)(base + 256);           // 256 ints
    int*            row_ptr = (int*)(base + 4096);          // N+1 ints
    unsigned int*   srt     = (unsigned int*)(base + 405504);    // E x 4B packed
    int2*           bkt     = (int2*)(base + 6805504);      // 196*9216*8 = 14.45 MB
    // bkt is dead after k_fine; h1 overlays it. xw is concurrent with bkt
    // (fat kernel) so it gets its own space.
    unsigned short* h1      = (unsigned short*)(base + 6805504);   // N*64 bf16
    unsigned short* xw      = (unsigned short*)(base + 21256192);  // N*64 bf16
    // total ws use ≈ 34.1 MB

    k_detect<<<1, 256, 0, stream>>>((const uint4*)x, (const int*)ei, flags, gcnt);

    // [bucket sort ∥ GEMM1] in one fat launch, then fine sort (scan inlined)
    k_build_gemm1<<<NBB + GB1, 256, 0, stream>>>(ea, ei, flags, gcnt, bkt,
                                                 x, W1, xw);
    k_fine<<<NBKT, 256, 0, stream>>>(bkt, gcnt, row_ptr, srt);

    // layer 1 (h1 overlays dead bkt)
    k_msg_csr<<<N_NODES / 4, 256, 0, stream>>>((const unsigned int*)xw, srt, row_ptr, b1, flags, h1, 0);

    // layer 2
    k_gemm2<<<N_NODES / 32, 256, 0, stream>>>((const unsigned int*)h1, W2, flags, xw);
    k_msg_csr<<<N_NODES / 4, 256, 0, stream>>>((const unsigned int*)xw, srt, row_ptr, b2, flags, d_out, 1);
}